// Round 10
// baseline (41.270 us; speedup 1.0000x reference)
//
#include <hip/hip_runtime.h>
#include <math.h>

// FrustumPointNetLoss for MI355X (gfx950).
//
// R10: remove the work-imbalance tail. In R9, blocks 0..15 did the batch body
//      (~2-3 us of trig + scattered gathers) PLUS a full 16-iteration mask
//      share -- an additive tail on the kernel's critical path. Now:
//        blocks 0..15   : batch body + 15 mask iterations (i=0..14)
//        blocks 16..31  : 16 iterations + 1 extra float4 (covers the hole)
//        blocks 32..2047: 16 iterations
//      Exact cover, all slices lane-contiguous (coalescing unchanged).
//
// ws layout (doubles):
//   [0 .. 2048)        mask-loss per-block partials
//   [2048 .. 2160)     batch-loss per-block partials (16 blocks x 7 sums)

constexpr int kNH = 12;
constexpr int kNS = 6;
constexpr int kBS = 4096;
constexpr int kNP = 4096;
constexpr float kPI = 3.14159265358979323846f;

constexpr int kTPB = 256;
constexpr int kMaskBlocks = 2048;                // == grid; one generation
constexpr int kF4 = (kBS * kNP) / 2;             // 8,388,608 float4s (2 rows each)
constexpr int kMaskThreads = kMaskBlocks * kTPB; // 524,288
constexpr int kIters = kF4 / kMaskThreads;       // 16
constexpr int kBatchBlocks = kBS / kTPB;         // 16
constexpr int kDutyThreads = kBatchBlocks * kTPB;  // 4096 (tid < this skip i=15)

typedef float vf4 __attribute__((ext_vector_type(4)));
typedef int vi2 __attribute__((ext_vector_type(2)));

__device__ __forceinline__ float wave_sum(float v) {
#pragma unroll
    for (int off = 32; off > 0; off >>= 1) v += __shfl_down(v, off, 64);
    return v;
}

__device__ __forceinline__ double wave_sum_d(double v) {
#pragma unroll
    for (int off = 32; off > 0; off >>= 1) v += __shfl_down(v, off, 64);
    return v;
}

__device__ __forceinline__ float huber_el(float e, float d) {
    float a = fabsf(e);
    float q = fminf(a, d);
    return 0.5f * q * q + d * (a - q);
}

// 2-class NLL: lse(s0,s1) - s_correct = softplus(s_other - s_correct)
__device__ __forceinline__ float row_nll2(float s0, float s1, int lb) {
    float x = lb ? (s0 - s1) : (s1 - s0);
    return fmaxf(x, 0.f) + __logf(1.f + __expf(-fabsf(x)));
}

__device__ void batch_loss_body(
        int bid,
        const float* __restrict__ center, const float* __restrict__ center_label,
        const float* __restrict__ stage1_center,
        const float* __restrict__ heading_scores,
        const float* __restrict__ hres_norm, const float* __restrict__ hres,
        const int* __restrict__ hcls_label, const float* __restrict__ hres_label,
        const float* __restrict__ size_scores,
        const float* __restrict__ sres_norm, const float* __restrict__ sres,
        const int* __restrict__ scls_label, const float* __restrict__ sres_label,
        const float* __restrict__ anchors, double* __restrict__ bpartials) {
    const int b = bid * kTPB + threadIdx.x;
    float v[7];  // center, stage1, hclass, hres, sclass, sres, corners
#pragma unroll
    for (int j = 0; j < 7; ++j) v[j] = 0.f;
    {
        const float cx = center[3 * b], cy = center[3 * b + 1], cz = center[3 * b + 2];
        const float glx = center_label[3 * b], gly = center_label[3 * b + 1],
                    glz = center_label[3 * b + 2];
        {
            float dx = cx - glx, dy = cy - gly, dz = cz - glz;
            v[0] = huber_el(sqrtf(dx * dx + dy * dy + dz * dz), 2.0f);
            float ex = cx - stage1_center[3 * b];
            float ey = cy - stage1_center[3 * b + 1];
            float ez = cz - stage1_center[3 * b + 2];
            v[1] = huber_el(sqrtf(ex * ex + ey * ey + ez * ez), 1.0f);
        }
        const int hc = hcls_label[b];
        const int sc = scls_label[b];
        {
            float m = -1e30f;
            for (int i = 0; i < kNH; ++i) m = fmaxf(m, heading_scores[b * kNH + i]);
            float se = 0.f;
            for (int i = 0; i < kNH; ++i) se += __expf(heading_scores[b * kNH + i] - m);
            v[2] = m + __logf(se) - heading_scores[b * kNH + hc];
        }
        {
            float m = -1e30f;
            for (int i = 0; i < kNS; ++i) m = fmaxf(m, size_scores[b * kNS + i]);
            float se = 0.f;
            for (int i = 0; i < kNS; ++i) se += __expf(size_scores[b * kNS + i] - m);
            v[4] = m + __logf(se) - size_scores[b * kNS + sc];
        }
        v[3] = huber_el(hres_norm[b * kNH + hc] - hres_label[b] * ((float)kNH / kPI), 1.0f);
        const float a0 = anchors[sc * 3 + 0];
        const float a1 = anchors[sc * 3 + 1];
        const float a2 = anchors[sc * 3 + 2];
        {
            float e0 = sres_label[3 * b + 0] / a0 - sres_norm[(b * kNS + sc) * 3 + 0];
            float e1 = sres_label[3 * b + 1] / a1 - sres_norm[(b * kNS + sc) * 3 + 1];
            float e2 = sres_label[3 * b + 2] / a2 - sres_norm[(b * kNS + sc) * 3 + 2];
            v[5] = huber_el(sqrtf(e0 * e0 + e1 * e1 + e2 * e2), 1.0f);
        }
        {
            const float bin = (float)hc * (2.0f * kPI / (float)kNH);
            const float hp = hres[b * kNH + hc] + bin;
            const float hg = hres_label[b] + bin;
            const float lp = a0 + 2.f * sres[(b * kNS + sc) * 3 + 0];
            const float wp = a1 + 2.f * sres[(b * kNS + sc) * 3 + 1];
            const float tp = a2 + 2.f * sres[(b * kNS + sc) * 3 + 2];
            const float lg = a0 + sres_label[3 * b + 0];
            const float wg = a1 + sres_label[3 * b + 1];
            const float tg = a2 + sres_label[3 * b + 2];
            const float cp = cosf(hp), sp = sinf(hp);
            const float cg = cosf(hg), sg = sinf(hg);
            const float SX[8] = {1, 1, -1, -1, 1, 1, -1, -1};
            const float SY[8] = {1, 1, 1, 1, -1, -1, -1, -1};
            const float SZ[8] = {1, -1, -1, 1, 1, -1, -1, 1};
            float cl = 0.f;
#pragma unroll
            for (int k = 0; k < 8; ++k) {
                float plx = 0.5f * lp * SX[k], ply = 0.5f * tp * SY[k], plz = 0.5f * wp * SZ[k];
                float px = cp * plx + sp * plz + cx;
                float py = ply + cy;
                float pz = -sp * plx + cp * plz + cz;
                float qlx = 0.5f * lg * SX[k], qly = 0.5f * tg * SY[k], qlz = 0.5f * wg * SZ[k];
                float rx = cg * qlx + sg * qlz;
                float rz = -sg * qlx + cg * qlz;
                float dgy = py - (qly + gly);
                float d1x = px - (rx + glx), d1z = pz - (rz + glz);
                float d2x = px - (-rx + glx), d2z = pz - (-rz + glz);
                float n1 = sqrtf(d1x * d1x + dgy * dgy + d1z * d1z);
                float n2 = sqrtf(d2x * d2x + dgy * dgy + d2z * d2z);
                cl += huber_el(fminf(n1, n2), 1.0f);
            }
            v[6] = cl;
        }
    }
    __shared__ float sb[4][7];
#pragma unroll
    for (int j = 0; j < 7; ++j) {
        float r = wave_sum(v[j]);
        if ((threadIdx.x & 63) == 0) sb[threadIdx.x >> 6][j] = r;
    }
    __syncthreads();
    if (threadIdx.x == 0) {
#pragma unroll
        for (int j = 0; j < 7; ++j)
            bpartials[bid * 7 + j] = (double)(sb[0][j] + sb[1][j] + sb[2][j] + sb[3][j]);
    }
    __syncthreads();
}

__global__ __launch_bounds__(256) void fused_loss_kernel(
        const float* __restrict__ logits, const int* __restrict__ labels,
        const float* __restrict__ center, const float* __restrict__ center_label,
        const float* __restrict__ stage1_center,
        const float* __restrict__ heading_scores,
        const float* __restrict__ hres_norm, const float* __restrict__ hres,
        const int* __restrict__ hcls_label, const float* __restrict__ hres_label,
        const float* __restrict__ size_scores,
        const float* __restrict__ sres_norm, const float* __restrict__ sres,
        const int* __restrict__ scls_label, const float* __restrict__ sres_label,
        const float* __restrict__ anchors, double* __restrict__ ws) {
    const bool duty = blockIdx.x < (unsigned)kBatchBlocks;
    if (duty) {
        batch_loss_body(blockIdx.x, center, center_label, stage1_center,
                        heading_scores, hres_norm, hres, hcls_label, hres_label,
                        size_scores, sres_norm, sres, scls_label, sres_label,
                        anchors, ws + kMaskBlocks);
    }
    const int tid = blockIdx.x * kTPB + threadIdx.x;
    const vf4* __restrict__ lg4 = reinterpret_cast<const vf4*>(logits);
    const vi2* __restrict__ lb2 = reinterpret_cast<const vi2*>(labels);
    float acc = 0.f;
    // Duty blocks run 15 iterations; everyone else 16.
    const int niter = duty ? (kIters - 1) : kIters;
#pragma unroll 4
    for (int i = 0; i < niter; ++i) {
        const int idx = i * kMaskThreads + tid;
        vf4 a = lg4[idx];
        vi2 lb = lb2[idx];
        acc += row_nll2(a[0], a[1], lb[0]);
        acc += row_nll2(a[2], a[3], lb[1]);
    }
    // Hole left by duty threads at i=15 (f4 indices [15*524288, 15*524288+4096)):
    // covered by blocks 16..31 (tid 4096..8191), one extra float4 each.
    if (blockIdx.x >= (unsigned)kBatchBlocks &&
        blockIdx.x < (unsigned)(2 * kBatchBlocks)) {
        const int idx = (kIters - 1) * kMaskThreads + (tid - kDutyThreads);
        vf4 a = lg4[idx];
        vi2 lb = lb2[idx];
        acc += row_nll2(a[0], a[1], lb[0]);
        acc += row_nll2(a[2], a[3], lb[1]);
    }
    acc = wave_sum(acc);
    __shared__ float s[4];
    if ((threadIdx.x & 63) == 0) s[threadIdx.x >> 6] = acc;
    __syncthreads();
    if (threadIdx.x == 0)
        ws[blockIdx.x] = (double)(s[0] + s[1] + s[2] + s[3]);
}

__global__ __launch_bounds__(256) void finalize_kernel(
        const double* __restrict__ partials, const double* __restrict__ bpartials,
        float* __restrict__ out) {
    double acc = 0.0;
#pragma unroll
    for (int i = 0; i < kMaskBlocks / kTPB; ++i)
        acc += partials[threadIdx.x + i * kTPB];
    acc = wave_sum_d(acc);
    __shared__ double s[4];
    if ((threadIdx.x & 63) == 0) s[threadIdx.x >> 6] = acc;
    __syncthreads();
    if (threadIdx.x == 0) {
        const double mask_sum = s[0] + s[1] + s[2] + s[3];
        double bsum[7] = {0, 0, 0, 0, 0, 0, 0};
        for (int blk = 0; blk < kBatchBlocks; ++blk)
#pragma unroll
            for (int j = 0; j < 7; ++j) bsum[j] += bpartials[blk * 7 + j];
        const double inv_rows = 1.0 / ((double)kBS * (double)kNP);
        const double inv_bs = 1.0 / (double)kBS;
        float mask_l = (float)(mask_sum * inv_rows);
        float center_l = (float)(bsum[0] * inv_bs);
        float stage1_l = (float)(bsum[1] * inv_bs);
        float hclass_l = (float)(bsum[2] * inv_bs);
        float hres_l20 = (float)(bsum[3] * inv_bs * 20.0);
        float sclass_l = (float)(bsum[4] * inv_bs);
        float sres_l20 = (float)(bsum[5] * inv_bs * 20.0);
        float corners10 = (float)(bsum[6] * inv_bs * (1.0 / 8.0) * 10.0);
        float total = mask_l + center_l + hclass_l + sclass_l + hres_l20 + sres_l20 +
                      stage1_l + corners10;
        out[0] = total;
        out[1] = mask_l;
        out[2] = center_l;
        out[3] = hclass_l;
        out[4] = sclass_l;
        out[5] = hres_l20;
        out[6] = sres_l20;
        out[7] = stage1_l;
        out[8] = corners10;
    }
}

extern "C" void kernel_launch(void* const* d_in, const int* in_sizes, int n_in,
                              void* d_out, int out_size, void* d_ws, size_t ws_size,
                              hipStream_t stream) {
    const float* logits = (const float*)d_in[0];
    const int* mask_label = (const int*)d_in[1];
    const float* center = (const float*)d_in[2];
    const float* center_label = (const float*)d_in[3];
    const float* stage1_center = (const float*)d_in[4];
    const float* heading_scores = (const float*)d_in[5];
    const float* hres_norm = (const float*)d_in[6];
    const float* hres = (const float*)d_in[7];
    const int* hcls_label = (const int*)d_in[8];
    const float* hres_label = (const float*)d_in[9];
    const float* size_scores = (const float*)d_in[10];
    const float* sres_norm = (const float*)d_in[11];
    const float* sres = (const float*)d_in[12];
    const int* scls_label = (const int*)d_in[13];
    const float* sres_label = (const float*)d_in[14];
    const float* anchors = (const float*)d_in[15];

    double* ws = (double*)d_ws;  // [0..2048) mask partials, [2048..2160) batch

    fused_loss_kernel<<<kMaskBlocks, kTPB, 0, stream>>>(
        logits, mask_label, center, center_label, stage1_center, heading_scores,
        hres_norm, hres, hcls_label, hres_label, size_scores, sres_norm, sres,
        scls_label, sres_label, anchors, ws);
    finalize_kernel<<<1, kTPB, 0, stream>>>(ws, ws + kMaskBlocks, (float*)d_out);
}